// Round 2
// baseline (120.770 us; speedup 1.0000x reference)
//
#include <hip/hip_runtime.h>
#include <hip/hip_bf16.h>

// Problem constants
#define WH 256          // 16*16
#define NB 8            // batch
#define CSLOW 1024
#define CFAST 256
#define CCAT 2048
#define COUT 1024
#define CFEAT 2048
#define NROIS 128
#define FEATSZ 4194304  // 8*2048*256
#define ROISZ  262144   // 8*16*2048

typedef short s16x4 __attribute__((ext_vector_type(4)));
typedef short s16x8 __attribute__((ext_vector_type(8)));
typedef float f32x4 __attribute__((ext_vector_type(4)));

__device__ inline void gld_lds16(void* lds, const void* g) {
  __builtin_amdgcn_global_load_lds(
      (const __attribute__((address_space(1))) unsigned int*)g,
      (__attribute__((address_space(3))) unsigned int*)lds,
      16, 0, 0);
}

__device__ inline unsigned short bf16u(float v) {
  __hip_bfloat16 h = __float2bfloat16(v);
  return *(unsigned short*)&h;
}

// ---------------------------------------------------------------------------
// K1: slow/fast rearrange + temporal pool (8->2 by mean of 4) + concat,
//     output transposed as FpT[col][c] bf16, col=(b*2+t)*256+wh.
// grid: b(8) * t(2) * cb(32) * wq(4) = 2048 blocks (8/CU), 256 threads.
// Block tile: 64 channels x 64 wh. 16 independent float4 loads per thread.
// ---------------------------------------------------------------------------
__global__ __launch_bounds__(256) void pool_transpose_kernel(
    const float* __restrict__ slow, const float* __restrict__ fast,
    __hip_bfloat16* __restrict__ FpT)
{
  __shared__ unsigned short tile[64][68];  // [c_local][wh_local], pad to 68
  int blk = blockIdx.x;
  int wq = blk & 3;
  int cb = (blk >> 2) & 31;
  int t  = (blk >> 7) & 1;
  int b  = blk >> 8;
  int tid = threadIdx.x;
  int whq = tid & 15;          // 16 quads -> 64 wh
  int cl  = tid >> 4;          // 16 channels per pass
  int wh  = wq * 64 + whq * 4;

  #pragma unroll
  for (int pass = 0; pass < 4; ++pass) {
    int c_local = pass * 16 + cl;
    int c = cb * 64 + c_local;
    float4 v0, v1, v2, v3;
    if (cb < 16) {  // uniform per block
      const float* p = slow + ((size_t)(b * CSLOW + c) * 8 + 4 * t) * WH + wh;
      v0 = *(const float4*)(p);
      v1 = *(const float4*)(p + WH);
      v2 = *(const float4*)(p + 2 * WH);
      v3 = *(const float4*)(p + 3 * WH);
    } else {
      int cp = c - CSLOW;
      int cf = cp & 255;
      int hi = cp >> 8;
      const float* p = fast + ((size_t)(b * CFAST + cf) * 32 + 16 * t + hi) * WH + wh;
      v0 = *(const float4*)(p);
      v1 = *(const float4*)(p + 4 * WH);
      v2 = *(const float4*)(p + 8 * WH);
      v3 = *(const float4*)(p + 12 * WH);
    }
    s16x4 o;
    o[0] = (short)bf16u(0.25f * (v0.x + v1.x + v2.x + v3.x));
    o[1] = (short)bf16u(0.25f * (v0.y + v1.y + v2.y + v3.y));
    o[2] = (short)bf16u(0.25f * (v0.z + v1.z + v2.z + v3.z));
    o[3] = (short)bf16u(0.25f * (v0.w + v1.w + v2.w + v3.w));
    *(s16x4*)&tile[c_local][whq * 4] = o;
  }
  __syncthreads();

  int l = tid & 63, w = tid >> 6;
  int col0 = (b * 2 + t) * 256 + wq * 64;
  int c0 = (l & 7) * 8;
  #pragma unroll
  for (int p = 0; p < 2; ++p) {
    int col_l = p * 32 + w * 8 + (l >> 3);
    s16x8 o;
    #pragma unroll
    for (int j = 0; j < 8; ++j)
      o[j] = (short)tile[c0 + j][col_l];
    *(s16x8*)(FpT + (size_t)(col0 + col_l) * 2048 + cb * 64 + c0) = o;
  }
}

// ---------------------------------------------------------------------------
// K2: conv_w fp32 -> bf16 cast. grid 2048 x 256, 4 elems/thread
// ---------------------------------------------------------------------------
__global__ __launch_bounds__(256) void castw_kernel(
    const float* __restrict__ W, __hip_bfloat16* __restrict__ Wb)
{
  int idx = (blockIdx.x * 256 + threadIdx.x) * 4;
  float4 v = *(const float4*)(W + idx);
  Wb[idx + 0] = __float2bfloat16(v.x);
  Wb[idx + 1] = __float2bfloat16(v.y);
  Wb[idx + 2] = __float2bfloat16(v.z);
  Wb[idx + 3] = __float2bfloat16(v.w);
}

// ---------------------------------------------------------------------------
// K3: GEMM  Y[o][col] = sum_c Wb[o][c] * FpT[col][c]
// M=1024, N=4096, K=2048. Tiles BM=128 BN=64 BK=64, 256 thr (4 waves 2x2),
// global_load_lds(16B) staging with pre-swizzled source (kslot ^= row&7).
// Split-K via blockIdx.z: each z computes kLen of K into its own Y partial.
// ---------------------------------------------------------------------------
__global__ __launch_bounds__(256) void gemm_kernel(
    const __hip_bfloat16* __restrict__ Wb,   // [1024][2048]
    const __hip_bfloat16* __restrict__ FpT,  // [4096][2048]
    float* __restrict__ Y, int kLen)         // [z][1024][4096]
{
  __shared__ unsigned short lA[128 * 64];
  __shared__ unsigned short lB[64 * 64];
  const int tid = threadIdx.x;
  const int lane = tid & 63;
  const int wid = tid >> 6;
  const int wm = wid >> 1, wn = wid & 1;
  const int nb = blockIdx.x, mb = blockIdx.y;
  const int kbase = blockIdx.z * kLen;
  float* Yp = Y + (size_t)blockIdx.z * 1024 * 4096;
  const int lr8 = lane >> 3;   // 0..7 (row within 8-row stripe)
  const int lk  = lane & 7;    // 0..7 (16B slot)

  f32x4 acc[4][2] = {};

  for (int k0i = 0; k0i < kLen; k0i += 64) {
    int k0 = kbase + k0i;
    __syncthreads();  // previous compute done reading LDS
    #pragma unroll
    for (int j = 0; j < 4; ++j) {
      int row = wid * 32 + j * 8 + lr8;
      int kslot = lk ^ (row & 7);
      const __hip_bfloat16* g = Wb + (size_t)(mb * 128 + row) * 2048 + k0 + kslot * 8;
      gld_lds16(&lA[(wid * 32 + j * 8) * 64], g);
    }
    #pragma unroll
    for (int j = 0; j < 2; ++j) {
      int row = wid * 16 + j * 8 + lr8;
      int kslot = lk ^ (row & 7);
      const __hip_bfloat16* g = FpT + (size_t)(nb * 64 + row) * 2048 + k0 + kslot * 8;
      gld_lds16(&lB[(wid * 16 + j * 8) * 64], g);
    }
    __syncthreads();

    #pragma unroll
    for (int s = 0; s < 2; ++s) {
      s16x8 af[4], bf[2];
      #pragma unroll
      for (int mi = 0; mi < 4; ++mi) {
        int row = wm * 64 + mi * 16 + (lane & 15);
        int kslot = (s * 4 + (lane >> 4)) ^ (row & 7);
        af[mi] = *(const s16x8*)((const char*)lA + (row << 7) + (kslot << 4));
      }
      #pragma unroll
      for (int ni = 0; ni < 2; ++ni) {
        int row = wn * 32 + ni * 16 + (lane & 15);
        int kslot = (s * 4 + (lane >> 4)) ^ (row & 7);
        bf[ni] = *(const s16x8*)((const char*)lB + (row << 7) + (kslot << 4));
      }
      #pragma unroll
      for (int mi = 0; mi < 4; ++mi)
        #pragma unroll
        for (int ni = 0; ni < 2; ++ni)
          acc[mi][ni] = __builtin_amdgcn_mfma_f32_16x16x32_bf16(af[mi], bf[ni], acc[mi][ni], 0, 0, 0);
    }
  }

  #pragma unroll
  for (int mi = 0; mi < 4; ++mi) {
    #pragma unroll
    for (int ni = 0; ni < 2; ++ni) {
      int col = nb * 64 + wn * 32 + ni * 16 + (lane & 15);
      int o0 = mb * 128 + wm * 64 + mi * 16 + (lane >> 4) * 4;
      #pragma unroll
      for (int r = 0; r < 4; ++r)
        Yp[(size_t)(o0 + r) * 4096 + col] = acc[mi][ni][r];
    }
  }
}

// ---------------------------------------------------------------------------
// K4: sum split-K partials + GroupNorm(16) + ReLU, write feat into d_out.
// grid 128 (b*16+g), 256 thr. Y1 may be null (no split).
// ---------------------------------------------------------------------------
__global__ __launch_bounds__(256) void gn_kernel(
    const float* __restrict__ Y0, const float* __restrict__ Y1,
    const float* __restrict__ gamma, const float* __restrict__ beta,
    float* __restrict__ out)
{
  __shared__ float red[8];
  __shared__ float stats[2];
  int b = blockIdx.x >> 4;
  int g = blockIdx.x & 15;
  int tid = threadIdx.x;
  int ol = tid >> 2;                 // 0..63 channel-in-group
  int cseg = (tid & 3) * 128;        // 0,128,256,384 within the 512 cols of b
  size_t off = (size_t)(g * 64 + ol) * 4096 + b * 512 + cseg;
  const float* src0 = Y0 + off;
  const float* src1 = Y1 ? (Y1 + off) : nullptr;
  float s = 0.f, ss = 0.f;
  for (int j = 0; j < 32; ++j) {
    float4 v = *(const float4*)(src0 + j * 4);
    if (src1) {
      float4 u = *(const float4*)(src1 + j * 4);
      v.x += u.x; v.y += u.y; v.z += u.z; v.w += u.w;
    }
    s += v.x + v.y + v.z + v.w;
    ss += v.x * v.x + v.y * v.y + v.z * v.z + v.w * v.w;
  }
  for (int off2 = 32; off2; off2 >>= 1) {
    s += __shfl_xor(s, off2);
    ss += __shfl_xor(ss, off2);
  }
  int lane = tid & 63, wid = tid >> 6;
  if (lane == 0) { red[wid] = s; red[wid + 4] = ss; }
  __syncthreads();
  if (tid == 0) {
    float S = red[0] + red[1] + red[2] + red[3];
    float SS = red[4] + red[5] + red[6] + red[7];
    float mu = S / 32768.f;
    float var = SS / 32768.f - mu * mu;
    stats[0] = mu;
    stats[1] = 1.0f / sqrtf(var + 1e-5f);
  }
  __syncthreads();
  float mu = stats[0], rstd = stats[1];
  int o = g * 64 + ol;
  float ga = gamma[o], be = beta[o];
  int tpool = cseg >> 8;
  int wh0 = cseg & 255;
  float* dst = out + ((size_t)(b * 2048 + o * 2 + tpool)) * 256 + wh0;
  for (int j = 0; j < 32; ++j) {
    float4 v = *(const float4*)(src0 + j * 4);
    if (src1) {
      float4 u = *(const float4*)(src1 + j * 4);
      v.x += u.x; v.y += u.y; v.z += u.z; v.w += u.w;
    }
    float4 r;
    r.x = fmaxf((v.x - mu) * rstd * ga + be, 0.f);
    r.y = fmaxf((v.y - mu) * rstd * ga + be, 0.f);
    r.z = fmaxf((v.z - mu) * rstd * ga + be, 0.f);
    r.w = fmaxf((v.w - mu) * rstd * ga + be, 0.f);
    *(float4*)(dst + j * 4) = r;
  }
}

// ---------------------------------------------------------------------------
// K5: wbar[n][q] = (1/256) sum_p Wmat[n,p,q]  (mmcv RoIAlign aligned=true,
// ratio=2, avg; includes the /4 sample count and /256 output-mean).
// ---------------------------------------------------------------------------
__global__ __launch_bounds__(256) void wbar_kernel(
    const float* __restrict__ rois, float* __restrict__ wbar)
{
  __shared__ float acc[256];
  int n = blockIdx.x;
  int tid = threadIdx.x;
  acc[tid] = 0.f;
  __syncthreads();
  const float* r = rois + n * 5;
  float x1 = r[1] * (1.f / 16.f) - 0.5f;
  float y1 = r[2] * (1.f / 16.f) - 0.5f;
  float x2 = r[3] * (1.f / 16.f) - 0.5f;
  float y2 = r[4] * (1.f / 16.f) - 0.5f;
  float bw = (x2 - x1) / 16.f;
  float bh = (y2 - y1) / 16.f;
  int py = tid >> 4, px = tid & 15;
  #pragma unroll
  for (int sy = 0; sy < 2; ++sy) {
    #pragma unroll
    for (int sx = 0; sx < 2; ++sx) {
      float gy = (float)py + (sy + 0.5f) * 0.5f;
      float gx = (float)px + (sx + 0.5f) * 0.5f;
      float Yv = y1 + gy * bh;
      float Xv = x1 + gx * bw;
      if (Yv >= -1.f && Yv <= 16.f && Xv >= -1.f && Xv <= 16.f) {
        float y = fmaxf(Yv, 0.f);
        float x = fmaxf(Xv, 0.f);
        float y0f = floorf(y);
        float x0f = floorf(x);
        bool ye = y0f >= 15.f;
        bool xe = x0f >= 15.f;
        int y0 = ye ? 15 : (int)y0f;
        int y1i = ye ? 15 : y0 + 1;
        int x0 = xe ? 15 : (int)x0f;
        int x1i = xe ? 15 : x0 + 1;
        float ly = ye ? 0.f : (y - y0f);
        float lx = xe ? 0.f : (x - x0f);
        float hy = 1.f - ly, hx = 1.f - lx;
        atomicAdd(&acc[y0 * 16 + x0], hy * hx);
        atomicAdd(&acc[y0 * 16 + x1i], hy * lx);
        atomicAdd(&acc[y1i * 16 + x0], ly * hx);
        atomicAdd(&acc[y1i * 16 + x1i], ly * lx);
      }
    }
  }
  __syncthreads();
  wbar[n * 256 + tid] = acc[tid] * (1.f / 1024.f);  // /4 samples /256 points
}

// ---------------------------------------------------------------------------
// K6: roi_feat[n][c] = sum_q wbar[n][q] feat[b][c][q];
//     roi_pos [n][c] = sum_q wbar[n][q] pos[c][q].
// ---------------------------------------------------------------------------
__global__ __launch_bounds__(256) void roi_kernel(
    const float* __restrict__ feat, const float* __restrict__ pos,
    const float* __restrict__ wbar, float* __restrict__ out)
{
  __shared__ float wl[16][256];
  __shared__ float sF[2][16][128];
  __shared__ float sP[2][16][128];
  int b = blockIdx.x >> 4;
  int chunk = blockIdx.x & 15;
  int tid = threadIdx.x;
  #pragma unroll
  for (int rr = 0; rr < 16; ++rr)
    wl[rr][tid] = wbar[(b * 16 + rr) * 256 + tid];
  __syncthreads();
  int ch_l = tid & 127;
  int half = tid >> 7;
  int ch = chunk * 128 + ch_l;
  const float* fb = feat + ((size_t)(b * 2048 + ch)) * 256 + half * 128;
  const float* pb = pos + (size_t)ch * 256 + half * 128;
  float accF[16] = {0.f}, accP[16] = {0.f};
  for (int q0 = 0; q0 < 128; q0 += 4) {
    float4 vf = *(const float4*)(fb + q0);
    float4 vp = *(const float4*)(pb + q0);
    int q = half * 128 + q0;
    #pragma unroll
    for (int rr = 0; rr < 16; ++rr) {
      float4 w = *(const float4*)&wl[rr][q];
      accF[rr] += w.x * vf.x + w.y * vf.y + w.z * vf.z + w.w * vf.w;
      accP[rr] += w.x * vp.x + w.y * vp.y + w.z * vp.z + w.w * vp.w;
    }
  }
  #pragma unroll
  for (int rr = 0; rr < 16; ++rr) {
    sF[half][rr][ch_l] = accF[rr];
    sP[half][rr][ch_l] = accP[rr];
  }
  __syncthreads();
  if (half == 0) {
    #pragma unroll
    for (int rr = 0; rr < 16; ++rr) {
      float vF = sF[0][rr][ch_l] + sF[1][rr][ch_l];
      float vP = sP[0][rr][ch_l] + sP[1][rr][ch_l];
      out[FEATSZ + (size_t)(b * 16 + rr) * 2048 + ch] = vF;
      out[FEATSZ + ROISZ + (size_t)(b * 16 + rr) * 2048 + ch] = vP;
    }
  }
}

// ---------------------------------------------------------------------------
extern "C" void kernel_launch(void* const* d_in, const int* in_sizes, int n_in,
                              void* d_out, int out_size, void* d_ws, size_t ws_size,
                              hipStream_t stream)
{
  (void)in_sizes; (void)n_in; (void)out_size;
  const float* slow   = (const float*)d_in[0];
  const float* fast   = (const float*)d_in[1];
  const float* rois   = (const float*)d_in[2];
  const float* pos    = (const float*)d_in[3];
  const float* conv_w = (const float*)d_in[4];
  const float* gamma  = (const float*)d_in[5];
  const float* beta   = (const float*)d_in[6];
  float* out = (float*)d_out;
  char* ws = (char*)d_ws;

  __hip_bfloat16* FpT = (__hip_bfloat16*)(ws);                        // 16 MB: [4096][2048] bf16
  __hip_bfloat16* Wb  = (__hip_bfloat16*)(ws + 16777216);             // 4 MB:  [1024][2048] bf16
  float* Y            = (float*)(ws + 16777216 + 4194304);            // 16|32 MB: split-K partials
  // workspace need with split-K=2: 16M + 4M + 32M + 128K
  const size_t NEED2 = 16777216ull + 4194304ull + 33554432ull + 131072ull;
  const int nsplit = (ws_size >= NEED2) ? 2 : 1;
  float* wbar = (float*)(ws + 16777216 + 4194304 + (size_t)nsplit * 16777216);

  pool_transpose_kernel<<<dim3(2048), dim3(256), 0, stream>>>(slow, fast, FpT);
  castw_kernel<<<dim3(2048), dim3(256), 0, stream>>>(conv_w, Wb);
  gemm_kernel<<<dim3(64, 8, nsplit), dim3(256), 0, stream>>>(Wb, FpT, Y, 2048 / nsplit);
  gn_kernel<<<dim3(128), dim3(256), 0, stream>>>(
      Y, nsplit == 2 ? (Y + 4194304) : nullptr, gamma, beta, out);
  wbar_kernel<<<dim3(128), dim3(256), 0, stream>>>(rois, wbar);
  roi_kernel<<<dim3(128), dim3(256), 0, stream>>>(out, pos, wbar, out);
}

// Round 3
// 106.357 us; speedup vs baseline: 1.1355x; 1.1355x over previous
//
#include <hip/hip_runtime.h>
#include <hip/hip_bf16.h>

// Problem constants
#define WH 256          // 16*16
#define FEATSZ 4194304  // 8*2048*256
#define ROISZ  262144   // 8*16*2048

typedef short s16x4 __attribute__((ext_vector_type(4)));
typedef short s16x8 __attribute__((ext_vector_type(8)));
typedef float f32x4 __attribute__((ext_vector_type(4)));

__device__ inline void gld_lds16(void* lds, const void* g) {
  __builtin_amdgcn_global_load_lds(
      (const __attribute__((address_space(1))) unsigned int*)g,
      (__attribute__((address_space(3))) unsigned int*)lds,
      16, 0, 0);
}

__device__ inline unsigned short bf16u(float v) {
  __hip_bfloat16 h = __float2bfloat16(v);
  return *(unsigned short*)&h;
}

// ---------------------------------------------------------------------------
// K1a: slow/fast rearrange + temporal pool (mean of 4) into Fp[c][col] bf16,
// col = (b*2+t)*256 + wh. Pure streaming: wave reads 4x1KB contiguous slices,
// writes 512B contiguous. Grid ordered c-outermost so the write stream is
// strictly sequential. grid 8192 x 256 (4 waves = 4 (c,b,t) units per block).
// ---------------------------------------------------------------------------
__global__ __launch_bounds__(256) void pool_kernel(
    const float* __restrict__ slow, const float* __restrict__ fast,
    __hip_bfloat16* __restrict__ Fp)
{
  int P = blockIdx.x * 4 + (threadIdx.x >> 6);  // (c*8 + b)*2 + t
  int lane = threadIdx.x & 63;
  int t = P & 1;
  int b = (P >> 1) & 7;
  int c = P >> 4;
  int wh = lane * 4;
  const float* p;
  int sstride;
  if (c < 1024) {
    p = slow + ((size_t)((b * 1024 + c) * 8 + 4 * t)) * WH + wh;
    sstride = WH;          // consecutive temporal slices
  } else {
    int cp = c - 1024;
    int cf = cp & 255, hi = cp >> 8;
    p = fast + ((size_t)((b * 256 + cf) * 32 + 16 * t + hi)) * WH + wh;
    sstride = 4 * WH;      // slices at t_f = 16t+hi + {0,4,8,12}
  }
  float4 v0 = *(const float4*)(p);
  float4 v1 = *(const float4*)(p + sstride);
  float4 v2 = *(const float4*)(p + 2 * sstride);
  float4 v3 = *(const float4*)(p + 3 * sstride);
  s16x4 o;
  o[0] = (short)bf16u(0.25f * (v0.x + v1.x + v2.x + v3.x));
  o[1] = (short)bf16u(0.25f * (v0.y + v1.y + v2.y + v3.y));
  o[2] = (short)bf16u(0.25f * (v0.z + v1.z + v2.z + v3.z));
  o[3] = (short)bf16u(0.25f * (v0.w + v1.w + v2.w + v3.w));
  *(s16x4*)(Fp + (size_t)c * 4096 + (b * 2 + t) * 256 + wh) = o;
}

// ---------------------------------------------------------------------------
// K1b: transpose Fp[c][col] -> FpT[col][c]. Block owns 16 full FpT rows
// (g = col/16) => writes 64KB perfectly contiguous. Phase 1: coalesced 16B
// loads + scattered u16 LDS writes; phase 2: conflict-free ds_read_b128 +
// sequential 16B global stores. grid 256 x 256, LDS 64KB.
// ---------------------------------------------------------------------------
__global__ __launch_bounds__(256) void transpose_kernel(
    const __hip_bfloat16* __restrict__ Fp, __hip_bfloat16* __restrict__ FpT)
{
  __shared__ unsigned short tile[16][2048];   // [col_local][c]
  int g = blockIdx.x;
  int tid = threadIdx.x;
  int h = tid & 1;
  int cbase = tid >> 1;
  #pragma unroll 4
  for (int it = 0; it < 16; ++it) {
    int c = it * 128 + cbase;
    s16x8 v = *(const s16x8*)((const char*)Fp + (size_t)c * 8192 + g * 32 + h * 16);
    #pragma unroll
    for (int j = 0; j < 8; ++j)
      tile[h * 8 + j][c] = (unsigned short)v[j];
  }
  __syncthreads();
  int w = tid >> 6, l = tid & 63;
  #pragma unroll
  for (int rr = 0; rr < 4; ++rr) {
    int r = w * 4 + rr;
    #pragma unroll
    for (int i = 0; i < 4; ++i) {
      s16x8 v = *(const s16x8*)&tile[r][i * 512 + l * 8];
      *(s16x8*)((char*)FpT + (size_t)(g * 16 + r) * 4096 + i * 1024 + l * 16) = v;
    }
  }
}

// ---------------------------------------------------------------------------
// K2: conv_w fp32 -> bf16 cast
// ---------------------------------------------------------------------------
__global__ __launch_bounds__(256) void castw_kernel(
    const float* __restrict__ W, __hip_bfloat16* __restrict__ Wb)
{
  int idx = (blockIdx.x * 256 + threadIdx.x) * 4;
  float4 v = *(const float4*)(W + idx);
  Wb[idx + 0] = __float2bfloat16(v.x);
  Wb[idx + 1] = __float2bfloat16(v.y);
  Wb[idx + 2] = __float2bfloat16(v.z);
  Wb[idx + 3] = __float2bfloat16(v.w);
}

// ---------------------------------------------------------------------------
// K3: GEMM  Y[o][col] = sum_c Wb[o][c] * FpT[col][c], M=1024 N=4096 K=2048.
// BM=128 BN=64 BK=64, 4 waves (2x2), global_load_lds(16B) pre-swizzled src.
// Epilogue: per-(block,wave) GN partial sums written to fixed slots (no
// atomics, deterministic). grid (64,8) = 512 blocks.
// ---------------------------------------------------------------------------
__global__ __launch_bounds__(256) void gemm_kernel(
    const __hip_bfloat16* __restrict__ Wb,   // [1024][2048]
    const __hip_bfloat16* __restrict__ FpT,  // [4096][2048]
    float* __restrict__ Y,                   // [1024][4096]
    float2* __restrict__ partials)           // [128 groups][16 slots]
{
  __shared__ unsigned short lA[128 * 64];
  __shared__ unsigned short lB[64 * 64];
  const int tid = threadIdx.x;
  const int lane = tid & 63;
  const int wid = tid >> 6;
  const int wm = wid >> 1, wn = wid & 1;
  const int nb = blockIdx.x, mb = blockIdx.y;
  const int lr8 = lane >> 3;
  const int lk  = lane & 7;

  f32x4 acc[4][2] = {};

  for (int k0 = 0; k0 < 2048; k0 += 64) {
    __syncthreads();
    #pragma unroll
    for (int j = 0; j < 4; ++j) {
      int row = wid * 32 + j * 8 + lr8;
      int kslot = lk ^ (row & 7);
      const __hip_bfloat16* g = Wb + (size_t)(mb * 128 + row) * 2048 + k0 + kslot * 8;
      gld_lds16(&lA[(wid * 32 + j * 8) * 64], g);
    }
    #pragma unroll
    for (int j = 0; j < 2; ++j) {
      int row = wid * 16 + j * 8 + lr8;
      int kslot = lk ^ (row & 7);
      const __hip_bfloat16* g = FpT + (size_t)(nb * 64 + row) * 2048 + k0 + kslot * 8;
      gld_lds16(&lB[(wid * 16 + j * 8) * 64], g);
    }
    __syncthreads();

    #pragma unroll
    for (int s = 0; s < 2; ++s) {
      s16x8 af[4], bf[2];
      #pragma unroll
      for (int mi = 0; mi < 4; ++mi) {
        int row = wm * 64 + mi * 16 + (lane & 15);
        int kslot = (s * 4 + (lane >> 4)) ^ (row & 7);
        af[mi] = *(const s16x8*)((const char*)lA + (row << 7) + (kslot << 4));
      }
      #pragma unroll
      for (int ni = 0; ni < 2; ++ni) {
        int row = wn * 32 + ni * 16 + (lane & 15);
        int kslot = (s * 4 + (lane >> 4)) ^ (row & 7);
        bf[ni] = *(const s16x8*)((const char*)lB + (row << 7) + (kslot << 4));
      }
      #pragma unroll
      for (int mi = 0; mi < 4; ++mi)
        #pragma unroll
        for (int ni = 0; ni < 2; ++ni)
          acc[mi][ni] = __builtin_amdgcn_mfma_f32_16x16x32_bf16(af[mi], bf[ni], acc[mi][ni], 0, 0, 0);
    }
  }

  // C-write: C/D mapping col=lane&15, row=(lane>>4)*4+reg (m89/m91-verified)
  float s = 0.f, ss = 0.f;
  #pragma unroll
  for (int mi = 0; mi < 4; ++mi) {
    #pragma unroll
    for (int ni = 0; ni < 2; ++ni) {
      int col = nb * 64 + wn * 32 + ni * 16 + (lane & 15);
      int o0 = mb * 128 + wm * 64 + mi * 16 + (lane >> 4) * 4;
      #pragma unroll
      for (int r = 0; r < 4; ++r) {
        float v = acc[mi][ni][r];
        Y[(size_t)(o0 + r) * 4096 + col] = v;
        s += v;
        ss += v * v;
      }
    }
  }
  // wave covers only group g = 2*mb + wm; reduce and write fixed slot
  #pragma unroll
  for (int off = 32; off; off >>= 1) {
    s += __shfl_xor(s, off);
    ss += __shfl_xor(ss, off);
  }
  if (lane == 0) {
    int b = nb >> 3;
    int g = 2 * mb + wm;
    partials[(b * 16 + g) * 16 + (nb & 7) * 2 + wn] = make_float2(s, ss);
  }
}

// ---------------------------------------------------------------------------
// K4: GroupNorm normalize + ReLU + (c t) interleave into d_out.
// grid 2048 = ((b*16+g)*16 + q), 256 thr; each thread 8 elems.
// ---------------------------------------------------------------------------
__global__ __launch_bounds__(256) void gn_kernel(
    const float* __restrict__ Y, const float2* __restrict__ partials,
    const float* __restrict__ gamma, const float* __restrict__ beta,
    float* __restrict__ out)
{
  int blk = blockIdx.x;
  int q = blk & 15;
  int bg = blk >> 4;            // b*16 + g
  int b = bg >> 4, g = bg & 15;
  const float2* pp = partials + bg * 16;
  float S = 0.f, SS = 0.f;
  #pragma unroll
  for (int j = 0; j < 16; ++j) { float2 v = pp[j]; S += v.x; SS += v.y; }
  float mu = S * (1.f / 32768.f);
  float var = SS * (1.f / 32768.f) - mu * mu;
  float rstd = rsqrtf(var + 1e-5f);

  int tid = threadIdx.x;
  int o_l = q * 4 + (tid >> 6);
  int o = g * 64 + o_l;
  int colpos = (tid & 63) * 8;  // within 512 cols of batch b
  const float* src = Y + (size_t)o * 4096 + b * 512 + colpos;
  float ga = gamma[o] * rstd, be = beta[o] - mu * rstd * gamma[o];
  int t = colpos >> 8, wh = colpos & 255;
  float* dst = out + ((size_t)(b * 2048 + o * 2 + t)) * 256 + wh;
  #pragma unroll
  for (int j = 0; j < 2; ++j) {
    float4 v = *(const float4*)(src + j * 4);
    float4 r;
    r.x = fmaxf(v.x * ga + be, 0.f);
    r.y = fmaxf(v.y * ga + be, 0.f);
    r.z = fmaxf(v.z * ga + be, 0.f);
    r.w = fmaxf(v.w * ga + be, 0.f);
    *(float4*)(dst + j * 4) = r;
  }
}

// ---------------------------------------------------------------------------
// K5: wbar[n][q] = (1/256) sum_p Wmat[n,p,q] (mmcv RoIAlign aligned=true,
// ratio=2, avg; includes /4 samples and /256 output-mean).
// ---------------------------------------------------------------------------
__global__ __launch_bounds__(256) void wbar_kernel(
    const float* __restrict__ rois, float* __restrict__ wbar)
{
  __shared__ float acc[256];
  int n = blockIdx.x;
  int tid = threadIdx.x;
  acc[tid] = 0.f;
  __syncthreads();
  const float* r = rois + n * 5;
  float x1 = r[1] * (1.f / 16.f) - 0.5f;
  float y1 = r[2] * (1.f / 16.f) - 0.5f;
  float x2 = r[3] * (1.f / 16.f) - 0.5f;
  float y2 = r[4] * (1.f / 16.f) - 0.5f;
  float bw = (x2 - x1) / 16.f;
  float bh = (y2 - y1) / 16.f;
  int py = tid >> 4, px = tid & 15;
  #pragma unroll
  for (int sy = 0; sy < 2; ++sy) {
    #pragma unroll
    for (int sx = 0; sx < 2; ++sx) {
      float gy = (float)py + (sy + 0.5f) * 0.5f;
      float gx = (float)px + (sx + 0.5f) * 0.5f;
      float Yv = y1 + gy * bh;
      float Xv = x1 + gx * bw;
      if (Yv >= -1.f && Yv <= 16.f && Xv >= -1.f && Xv <= 16.f) {
        float y = fmaxf(Yv, 0.f);
        float x = fmaxf(Xv, 0.f);
        float y0f = floorf(y);
        float x0f = floorf(x);
        bool ye = y0f >= 15.f;
        bool xe = x0f >= 15.f;
        int y0 = ye ? 15 : (int)y0f;
        int y1i = ye ? 15 : y0 + 1;
        int x0 = xe ? 15 : (int)x0f;
        int x1i = xe ? 15 : x0 + 1;
        float ly = ye ? 0.f : (y - y0f);
        float lx = xe ? 0.f : (x - x0f);
        float hy = 1.f - ly, hx = 1.f - lx;
        atomicAdd(&acc[y0 * 16 + x0], hy * hx);
        atomicAdd(&acc[y0 * 16 + x1i], hy * lx);
        atomicAdd(&acc[y1i * 16 + x0], ly * hx);
        atomicAdd(&acc[y1i * 16 + x1i], ly * lx);
      }
    }
  }
  __syncthreads();
  wbar[n * 256 + tid] = acc[tid] * (1.f / 1024.f);
}

// ---------------------------------------------------------------------------
// K6: roi_feat[n][c] = sum_q wbar[n][q] feat[b][c][q];
//     roi_pos [n][c] = sum_q wbar[n][q] pos[c][q].
// ---------------------------------------------------------------------------
__global__ __launch_bounds__(256) void roi_kernel(
    const float* __restrict__ feat, const float* __restrict__ pos,
    const float* __restrict__ wbar, float* __restrict__ out)
{
  __shared__ float wl[16][256];
  __shared__ float sF[2][16][128];
  __shared__ float sP[2][16][128];
  int b = blockIdx.x >> 4;
  int chunk = blockIdx.x & 15;
  int tid = threadIdx.x;
  #pragma unroll
  for (int rr = 0; rr < 16; ++rr)
    wl[rr][tid] = wbar[(b * 16 + rr) * 256 + tid];
  __syncthreads();
  int ch_l = tid & 127;
  int half = tid >> 7;
  int ch = chunk * 128 + ch_l;
  const float* fb = feat + ((size_t)(b * 2048 + ch)) * 256 + half * 128;
  const float* pb = pos + (size_t)ch * 256 + half * 128;
  float accF[16] = {0.f}, accP[16] = {0.f};
  for (int q0 = 0; q0 < 128; q0 += 4) {
    float4 vf = *(const float4*)(fb + q0);
    float4 vp = *(const float4*)(pb + q0);
    int q = half * 128 + q0;
    #pragma unroll
    for (int rr = 0; rr < 16; ++rr) {
      float4 w = *(const float4*)&wl[rr][q];
      accF[rr] += w.x * vf.x + w.y * vf.y + w.z * vf.z + w.w * vf.w;
      accP[rr] += w.x * vp.x + w.y * vp.y + w.z * vp.z + w.w * vp.w;
    }
  }
  #pragma unroll
  for (int rr = 0; rr < 16; ++rr) {
    sF[half][rr][ch_l] = accF[rr];
    sP[half][rr][ch_l] = accP[rr];
  }
  __syncthreads();
  if (half == 0) {
    #pragma unroll
    for (int rr = 0; rr < 16; ++rr) {
      float vF = sF[0][rr][ch_l] + sF[1][rr][ch_l];
      float vP = sP[0][rr][ch_l] + sP[1][rr][ch_l];
      out[FEATSZ + (size_t)(b * 16 + rr) * 2048 + ch] = vF;
      out[FEATSZ + ROISZ + (size_t)(b * 16 + rr) * 2048 + ch] = vP;
    }
  }
}

// ---------------------------------------------------------------------------
extern "C" void kernel_launch(void* const* d_in, const int* in_sizes, int n_in,
                              void* d_out, int out_size, void* d_ws, size_t ws_size,
                              hipStream_t stream)
{
  (void)in_sizes; (void)n_in; (void)out_size; (void)ws_size;
  const float* slow   = (const float*)d_in[0];
  const float* fast   = (const float*)d_in[1];
  const float* rois   = (const float*)d_in[2];
  const float* pos    = (const float*)d_in[3];
  const float* conv_w = (const float*)d_in[4];
  const float* gamma  = (const float*)d_in[5];
  const float* beta   = (const float*)d_in[6];
  float* out = (float*)d_out;
  char* ws = (char*)d_ws;

  // Workspace layout (37.77 MB total, within the 37.9 MB proven available):
  //   [0, 16M)   Fp [2048][4096] bf16  -- dead after transpose; Y aliases it
  //   [16M,32M)  FpT [4096][2048] bf16 -- dead after gemm; wbar aliases it
  //   [32M,36M)  Wb [1024][2048] bf16
  //   [36M,+16K) partials [128][16] float2
  __hip_bfloat16* Fp  = (__hip_bfloat16*)(ws);
  __hip_bfloat16* FpT = (__hip_bfloat16*)(ws + (16u << 20));
  __hip_bfloat16* Wb  = (__hip_bfloat16*)(ws + (32u << 20));
  float*  Y           = (float*)(ws);                 // alias Fp
  float2* partials    = (float2*)(ws + (36u << 20));
  float*  wbar        = (float*)(ws + (16u << 20));   // alias FpT

  pool_kernel<<<dim3(8192), dim3(256), 0, stream>>>(slow, fast, Fp);
  transpose_kernel<<<dim3(256), dim3(256), 0, stream>>>(Fp, FpT);
  castw_kernel<<<dim3(2048), dim3(256), 0, stream>>>(conv_w, Wb);
  gemm_kernel<<<dim3(64, 8), dim3(256), 0, stream>>>(Wb, FpT, Y, partials);
  gn_kernel<<<dim3(2048), dim3(256), 0, stream>>>(Y, partials, gamma, beta, out);
  wbar_kernel<<<dim3(128), dim3(256), 0, stream>>>(rois, wbar);
  roi_kernel<<<dim3(128), dim3(256), 0, stream>>>(out, pos, wbar, out);
}